// Round 1
// baseline (1983.041 us; speedup 1.0000x reference)
//
#include <hip/hip_runtime.h>
#include <math.h>

// Problem constants
#define BB    4096   // batch
#define LL    30     // seq len
#define WW    5      // window
#define AA    30     // alphabet
#define EE    128    // embed dim
#define CC    40     // conv channels
#define HH    128    // lstm units
#define TT    3      // crf tags
#define K_ALL 328    // 200 (features) + 128 (h)
#define NB    16     // batch rows per LSTM block

// Workspace layout (in floats)
#define WS_P    0                         // P'[3][30][40] conv collapsed + bn1 folded
#define WS_BC   3600                      // biasC[40]
#define WS_BG   3648                      // biasG[2][512]
#define WS_WFC  4672                      // Wfc[2][3][128]  (fc folded with bn2)
#define WS_EB   5440                      // ebias[3]
#define WS_WT   5504                      // Wt[2][328][512] transposed [k][gate]
#define WS_EMIS (5504 + 2*328*512)        // emis[2][B][L][3] partial emissions
// total = 1,078,656 floats = 4.32 MB

__device__ __forceinline__ float sigm(float x) { return 1.0f / (1.0f + expf(-x)); }

// ---------------------------------------------------------------------------
// Kernel 1: fold BN1 into conv tables, transpose LSTM weights, fold BN2 into FC
// ---------------------------------------------------------------------------
__global__ void prep_kernel(const float* __restrict__ emb, const float* __restrict__ conv_w,
                            const float* __restrict__ conv_b,
                            const float* __restrict__ bn1_g, const float* __restrict__ bn1_b,
                            const float* __restrict__ bn1_m, const float* __restrict__ bn1_v,
                            const float* __restrict__ w_ih_f, const float* __restrict__ w_hh_f,
                            const float* __restrict__ b_f,
                            const float* __restrict__ w_ih_b, const float* __restrict__ w_hh_b,
                            const float* __restrict__ b_b,
                            const float* __restrict__ bn2_g, const float* __restrict__ bn2_b,
                            const float* __restrict__ bn2_m, const float* __restrict__ bn2_v,
                            const float* __restrict__ fc_w, const float* __restrict__ fc_b,
                            float* __restrict__ ws)
{
    const int gid = blockIdx.x * blockDim.x + threadIdx.x;
    const int gsz = gridDim.x * blockDim.x;

    // P'[k][a][c] = s1[c] * sum_e emb[a,e] * conv_w[c,e,k]
    for (int idx = gid; idx < 3600; idx += gsz) {
        int k = idx / 1200, rem = idx % 1200, a = rem / 40, c = rem % 40;
        float s1 = bn1_g[c] / sqrtf(bn1_v[c] + 1e-5f);
        float acc = 0.f;
        for (int e = 0; e < EE; ++e)
            acc += emb[a * EE + e] * conv_w[(c * EE + e) * 3 + k];
        ws[WS_P + idx] = acc * s1;
    }
    for (int c = gid; c < CC; c += gsz) {
        float s1 = bn1_g[c] / sqrtf(bn1_v[c] + 1e-5f);
        ws[WS_BC + c] = (conv_b[c] - bn1_m[c]) * s1 + bn1_b[c];
    }
    for (int i = gid; i < 1024; i += gsz) {
        int d = i >> 9, g = i & 511;
        ws[WS_BG + i] = d ? b_b[g] : b_f[g];
    }
    // Wfc[d][t][u] = fc_w[t][d*128+u] * s2[d*128+u]
    for (int i = gid; i < 768; i += gsz) {
        int d = i / 384, r = i % 384, t = r / 128, u = r % 128;
        int j = d * 128 + u;
        float s2 = bn2_g[j] / sqrtf(bn2_v[j] + 1e-5f);
        ws[WS_WFC + i] = fc_w[t * 256 + j] * s2;
    }
    for (int t = gid; t < TT; t += gsz) {
        float acc = fc_b[t];
        for (int j = 0; j < 256; ++j) {
            float s2 = bn2_g[j] / sqrtf(bn2_v[j] + 1e-5f);
            acc += fc_w[t * 256 + j] * (bn2_b[j] - bn2_m[j] * s2);
        }
        ws[WS_EB + t] = acc;
    }
    // Wt[d][k][g]: k<200 -> w_ih[g][k]; k>=200 -> w_hh[g][k-200]
    for (int i = gid; i < 2 * K_ALL * 512; i += gsz) {
        int d = i / (K_ALL * 512), r = i % (K_ALL * 512), k = r / 512, g = r % 512;
        const float* wih = d ? w_ih_b : w_ih_f;
        const float* whh = d ? w_hh_b : w_hh_f;
        ws[WS_WT + i] = (k < 200) ? wih[g * 200 + k] : whh[g * HH + (k - 200)];
    }
}

// ---------------------------------------------------------------------------
// Kernel 2: fused features + BiLSTM + partial emissions.
// Grid: 512 blocks = 2 dirs x 256 batch-tiles of NB=16 rows. 256 threads.
// Per step: features -> A[:, :200] (from token tables), GEMM
// Z[16][512] = A[16][328] x Wt, thread-local gates (each thread owns all 4
// gates of its (row, unit) pairs -> no Z exchange), h -> A[:, 200:328].
// ---------------------------------------------------------------------------
__global__ __launch_bounds__(256, 2)
void lstm_kernel(const int* __restrict__ x, float* __restrict__ ws)
{
    __shared__ float A[NB][336];        // [features(200) | h(128)], padded
    __shared__ float Wst[16][512];      // staged weight K-chunk
    __shared__ float biasG_s[512];
    __shared__ float Wfc_s[384];
    __shared__ float biasC_s[40];

    const int tid  = threadIdx.x;
    const int d    = blockIdx.x & 1;
    const int tile = blockIdx.x >> 1;
    const int b0   = tile * NB;

    const float* Wt = ws + WS_WT + d * (K_ALL * 512);
    const float* Pp = ws + WS_P;
    float* emis = ws + WS_EMIS + d * (BB * LL * TT);

    for (int i = tid; i < 512; i += 256) biasG_s[i] = ws[WS_BG + d * 512 + i];
    for (int i = tid; i < 384; i += 256) Wfc_s[i]   = ws[WS_WFC + d * 384 + i];
    for (int i = tid; i < 40;  i += 256) biasC_s[i] = ws[WS_BC + i];
    for (int i = tid; i < NB * HH; i += 256) A[i / HH][200 + (i % HH)] = 0.f;

    const int cg = tid & 63;     // column group: units u0, u0+1 (all 4 gates)
    const int rg = tid >> 6;     // wave index = row group (rows are wave-uniform)
    const int r0 = rg * 4;
    const int u0 = cg * 2;

    float cst[4][2];
    #pragma unroll
    for (int i = 0; i < 4; ++i) { cst[i][0] = 0.f; cst[i][1] = 0.f; }

    __syncthreads();

    for (int step = 0; step < LL; ++step) {
        const int l = d ? (LL - 1 - step) : step;

        // ---- features: conv(3-tap table lookups) + relu + maxpool ----
        for (int p = tid; p < NB * CC; p += 256) {
            int bb = p / CC, c = p % CC;
            const int* tok = x + (((b0 + bb) * LL) + l) * WW;
            int t0 = tok[0], t1 = tok[1], t2 = tok[2], t3 = tok[3], t4 = tok[4];
            float bc = biasC_s[c];
            float a0 = bc + Pp[(30 + t0) * 40 + c]  + Pp[(60 + t1) * 40 + c];
            float a1 = bc + Pp[t0 * 40 + c] + Pp[(30 + t1) * 40 + c] + Pp[(60 + t2) * 40 + c];
            float a2 = bc + Pp[t1 * 40 + c] + Pp[(30 + t2) * 40 + c] + Pp[(60 + t3) * 40 + c];
            float a3 = bc + Pp[t2 * 40 + c] + Pp[(30 + t3) * 40 + c] + Pp[(60 + t4) * 40 + c];
            float a4 = bc + Pp[t3 * 40 + c] + Pp[(30 + t4) * 40 + c];
            a0 = fmaxf(a0, 0.f); a1 = fmaxf(a1, 0.f); a2 = fmaxf(a2, 0.f);
            a3 = fmaxf(a3, 0.f); a4 = fmaxf(a4, 0.f);
            float* Af = &A[bb][c * 5];
            Af[0] = fmaxf(a0, a1);
            Af[1] = fmaxf(fmaxf(a0, a1), a2);
            Af[2] = fmaxf(fmaxf(a1, a2), a3);
            Af[3] = fmaxf(fmaxf(a2, a3), a4);
            Af[4] = fmaxf(a3, a4);
        }
        __syncthreads();

        // ---- GEMM: acc[i][g*2+du] = sum_k A[r0+i][k] * Wt[k][g*128+u0+du] ----
        float acc[4][8];
        #pragma unroll
        for (int i = 0; i < 4; ++i)
            #pragma unroll
            for (int j = 0; j < 8; ++j) acc[i][j] = 0.f;

        for (int kc = 0; kc < 320; kc += 16) {
            const float4* src = (const float4*)(Wt + kc * 512);
            float4* dst = (float4*)&Wst[0][0];
            #pragma unroll
            for (int i = 0; i < 8; ++i) dst[tid + i * 256] = src[tid + i * 256];
            __syncthreads();
            #pragma unroll
            for (int kk = 0; kk < 16; ++kk) {
                const float* wrow = &Wst[kk][0];
                float2 w0 = *(const float2*)(wrow + u0);
                float2 w1 = *(const float2*)(wrow + 128 + u0);
                float2 w2 = *(const float2*)(wrow + 256 + u0);
                float2 w3 = *(const float2*)(wrow + 384 + u0);
                #pragma unroll
                for (int i = 0; i < 4; ++i) {
                    float av = A[r0 + i][kc + kk];
                    acc[i][0] = fmaf(av, w0.x, acc[i][0]);
                    acc[i][1] = fmaf(av, w0.y, acc[i][1]);
                    acc[i][2] = fmaf(av, w1.x, acc[i][2]);
                    acc[i][3] = fmaf(av, w1.y, acc[i][3]);
                    acc[i][4] = fmaf(av, w2.x, acc[i][4]);
                    acc[i][5] = fmaf(av, w2.y, acc[i][5]);
                    acc[i][6] = fmaf(av, w3.x, acc[i][6]);
                    acc[i][7] = fmaf(av, w3.y, acc[i][7]);
                }
            }
            __syncthreads();
        }
        {   // tail chunk: k = 320..327
            const float4* src = (const float4*)(Wt + 320 * 512);
            float4* dst = (float4*)&Wst[0][0];
            #pragma unroll
            for (int i = 0; i < 4; ++i) dst[tid + i * 256] = src[tid + i * 256];
            __syncthreads();
            #pragma unroll
            for (int kk = 0; kk < 8; ++kk) {
                const float* wrow = &Wst[kk][0];
                float2 w0 = *(const float2*)(wrow + u0);
                float2 w1 = *(const float2*)(wrow + 128 + u0);
                float2 w2 = *(const float2*)(wrow + 256 + u0);
                float2 w3 = *(const float2*)(wrow + 384 + u0);
                #pragma unroll
                for (int i = 0; i < 4; ++i) {
                    float av = A[r0 + i][320 + kk];
                    acc[i][0] = fmaf(av, w0.x, acc[i][0]);
                    acc[i][1] = fmaf(av, w0.y, acc[i][1]);
                    acc[i][2] = fmaf(av, w1.x, acc[i][2]);
                    acc[i][3] = fmaf(av, w1.y, acc[i][3]);
                    acc[i][4] = fmaf(av, w2.x, acc[i][4]);
                    acc[i][5] = fmaf(av, w2.y, acc[i][5]);
                    acc[i][6] = fmaf(av, w3.x, acc[i][6]);
                    acc[i][7] = fmaf(av, w3.y, acc[i][7]);
                }
            }
            __syncthreads();
        }

        // ---- gates (thread-local: this thread owns i,f,g,o of its units) ----
        #pragma unroll
        for (int i = 0; i < 4; ++i) {
            #pragma unroll
            for (int j = 0; j < 2; ++j) {
                int u = u0 + j;
                float zi = acc[i][0 + j] + biasG_s[u];
                float zf = acc[i][2 + j] + biasG_s[128 + u];
                float zg = acc[i][4 + j] + biasG_s[256 + u];
                float zo = acc[i][6 + j] + biasG_s[384 + u];
                float cn = sigm(zf) * cst[i][j] + sigm(zi) * tanhf(zg);
                float h  = sigm(zo) * tanhf(cn);
                cst[i][j] = cn;
                A[r0 + i][200 + u] = h;
            }
        }
        __syncthreads();

        // ---- partial emissions for this (l): 3 dots of 128 per row ----
        if (tid < NB * TT) {
            int bb = tid / TT, t = tid % TT;
            float s = 0.f;
            for (int u = 0; u < HH; ++u)
                s += A[bb][200 + u] * Wfc_s[t * HH + u];
            emis[(((b0 + bb) * LL) + l) * TT + t] = s;
        }
        // no barrier needed: next feature phase writes A[:, :200] only,
        // emission reads A[:, 200:328]; disjoint. h overwrite is after the
        // next step's barriers.
    }
}

// ---------------------------------------------------------------------------
// Kernel 3: Viterbi decode. One thread per batch row.
// ---------------------------------------------------------------------------
__global__ void viterbi_kernel(const int* __restrict__ x, const float* __restrict__ ws,
                               const float* __restrict__ trans,
                               const float* __restrict__ start_t,
                               const float* __restrict__ end_t,
                               float* __restrict__ out)
{
    int b = blockIdx.x * blockDim.x + threadIdx.x;
    if (b >= BB) return;
    const float* eF = ws + WS_EMIS;
    const float* eB = ws + WS_EMIS + BB * LL * TT;
    const float eb0 = ws[WS_EB + 0], eb1 = ws[WS_EB + 1], eb2 = ws[WS_EB + 2];
    float tr[9];
    #pragma unroll
    for (int i = 0; i < 9; ++i) tr[i] = trans[i];

    int base = b * LL * TT;
    float s0 = start_t[0] + eF[base + 0] + eB[base + 0] + eb0;
    float s1 = start_t[1] + eF[base + 1] + eB[base + 1] + eb1;
    float s2 = start_t[2] + eF[base + 2] + eB[base + 2] + eb2;

    unsigned hist[LL - 1];
    unsigned maskbits = 0;

    #pragma unroll
    for (int l = 1; l < LL; ++l) {
        bool m = x[(b * LL + l) * WW + 2] > 0;
        if (m) maskbits |= (1u << l);
        int idx = base + l * TT;
        float e0 = eF[idx + 0] + eB[idx + 0] + eb0;
        float e1 = eF[idx + 1] + eB[idx + 1] + eb1;
        float e2 = eF[idx + 2] + eB[idx + 2] + eb2;

        float ns[3]; int pt[3];
        #pragma unroll
        for (int nt = 0; nt < 3; ++nt) {
            float c0 = s0 + tr[0 * 3 + nt];
            float c1 = s1 + tr[1 * 3 + nt];
            float c2 = s2 + tr[2 * 3 + nt];
            int p = 0; float bc = c0;
            if (c1 > bc) { bc = c1; p = 1; }   // strict '>': first-index argmax
            if (c2 > bc) { bc = c2; p = 2; }
            ns[nt] = bc; pt[nt] = p;
        }
        ns[0] += e0; ns[1] += e1; ns[2] += e2;
        hist[l - 1] = (unsigned)pt[0] | ((unsigned)pt[1] << 2) | ((unsigned)pt[2] << 4);
        if (m) { s0 = ns[0]; s1 = ns[1]; s2 = ns[2]; }
    }
    s0 += end_t[0]; s1 += end_t[1]; s2 += end_t[2];
    float best = s0; int last = 0;
    if (s1 > best) { best = s1; last = 1; }
    if (s2 > best) { best = s2; last = 2; }

    out[b] = best;
    float* tags = out + BB + b * LL;
    int tag = last;
    tags[LL - 1] = (float)last;
    #pragma unroll
    for (int l = LL - 1; l >= 1; --l) {
        int prev = (int)((hist[l - 1] >> (2 * tag)) & 3u);
        if (maskbits & (1u << l)) tag = prev;
        tags[l - 1] = (float)tag;
    }
}

// ---------------------------------------------------------------------------
extern "C" void kernel_launch(void* const* d_in, const int* in_sizes, int n_in,
                              void* d_out, int out_size, void* d_ws, size_t ws_size,
                              hipStream_t stream)
{
    const int*   x      = (const int*)  d_in[0];
    const float* emb    = (const float*)d_in[1];
    const float* conv_w = (const float*)d_in[2];
    const float* conv_b = (const float*)d_in[3];
    const float* bn1_g  = (const float*)d_in[4];
    const float* bn1_b  = (const float*)d_in[5];
    const float* bn1_m  = (const float*)d_in[6];
    const float* bn1_v  = (const float*)d_in[7];
    const float* w_ih_f = (const float*)d_in[8];
    const float* w_hh_f = (const float*)d_in[9];
    const float* b_f    = (const float*)d_in[10];
    const float* w_ih_b = (const float*)d_in[11];
    const float* w_hh_b = (const float*)d_in[12];
    const float* b_b    = (const float*)d_in[13];
    const float* bn2_g  = (const float*)d_in[14];
    const float* bn2_b  = (const float*)d_in[15];
    const float* bn2_m  = (const float*)d_in[16];
    const float* bn2_v  = (const float*)d_in[17];
    const float* fc_w   = (const float*)d_in[18];
    const float* fc_b   = (const float*)d_in[19];
    const float* trans  = (const float*)d_in[20];
    const float* start_t= (const float*)d_in[21];
    const float* end_t  = (const float*)d_in[22];

    float* ws  = (float*)d_ws;
    float* out = (float*)d_out;

    prep_kernel<<<256, 256, 0, stream>>>(emb, conv_w, conv_b,
                                         bn1_g, bn1_b, bn1_m, bn1_v,
                                         w_ih_f, w_hh_f, b_f,
                                         w_ih_b, w_hh_b, b_b,
                                         bn2_g, bn2_b, bn2_m, bn2_v,
                                         fc_w, fc_b, ws);
    lstm_kernel<<<512, 256, 0, stream>>>(x, ws);
    viterbi_kernel<<<16, 256, 0, stream>>>(x, ws, trans, start_t, end_t, out);
}

// Round 3
// 1715.577 us; speedup vs baseline: 1.1559x; 1.1559x over previous
//
#include <hip/hip_runtime.h>
#include <math.h>

// Problem constants
#define BB    4096   // batch
#define LL    30     // seq len
#define WW    5      // window
#define CC    40     // conv channels
#define HH    128    // lstm units
#define TT    3      // crf tags
#define KA    328    // 200 (features) + 128 (h)
#define NB    32     // batch rows per LSTM block

// Workspace layout (in floats)
#define WS_P    0                         // P'[3][30][40] conv collapsed + bn1 folded
#define WS_BC   3600                      // biasC[40]
#define WS_BG   3648                      // biasG[2][512]
#define WS_WFC  4672                      // Wfc[2][3][128]  (fc folded with bn2)
#define WS_EB   5440                      // ebias[3]
#define WS_WT   5504                      // Wt[2][328][512] transposed [k][gate]
#define WS_EMIS (5504 + 2*328*512)        // emis[2][B][L][3] partial emissions

__device__ __forceinline__ float sigm(float x) {
    return __builtin_amdgcn_rcpf(1.0f + __expf(-x));
}
__device__ __forceinline__ float tanh_fast(float x) {
    return 2.0f * __builtin_amdgcn_rcpf(1.0f + __expf(-2.0f * x)) - 1.0f;
}

__device__ __forceinline__ void async_copy16(const float* gp, const float* lp) {
    // global -> LDS direct DMA, 16B per lane. LDS dest = wave-uniform base + lane*16.
    __builtin_amdgcn_global_load_lds(
        (const __attribute__((address_space(1))) void*)gp,
        (__attribute__((address_space(3))) void*)lp, 16, 0, 0);
}

// ---------------------------------------------------------------------------
// Kernel 1: fold BN1 into conv tables, transpose LSTM weights, fold BN2 into FC
// ---------------------------------------------------------------------------
__global__ void prep_kernel(const float* __restrict__ emb, const float* __restrict__ conv_w,
                            const float* __restrict__ conv_b,
                            const float* __restrict__ bn1_g, const float* __restrict__ bn1_b,
                            const float* __restrict__ bn1_m, const float* __restrict__ bn1_v,
                            const float* __restrict__ w_ih_f, const float* __restrict__ w_hh_f,
                            const float* __restrict__ b_f,
                            const float* __restrict__ w_ih_b, const float* __restrict__ w_hh_b,
                            const float* __restrict__ b_b,
                            const float* __restrict__ bn2_g, const float* __restrict__ bn2_b,
                            const float* __restrict__ bn2_m, const float* __restrict__ bn2_v,
                            const float* __restrict__ fc_w, const float* __restrict__ fc_b,
                            float* __restrict__ ws)
{
    const int gid = blockIdx.x * blockDim.x + threadIdx.x;
    const int gsz = gridDim.x * blockDim.x;

    // P'[k][a][c] = s1[c] * sum_e emb[a,e] * conv_w[c,e,k]
    for (int idx = gid; idx < 3600; idx += gsz) {
        int k = idx / 1200, rem = idx % 1200, a = rem / 40, c = rem % 40;
        float s1 = bn1_g[c] / sqrtf(bn1_v[c] + 1e-5f);
        float acc = 0.f;
        for (int e = 0; e < 128; ++e)
            acc += emb[a * 128 + e] * conv_w[(c * 128 + e) * 3 + k];
        ws[WS_P + idx] = acc * s1;
    }
    for (int c = gid; c < CC; c += gsz) {
        float s1 = bn1_g[c] / sqrtf(bn1_v[c] + 1e-5f);
        ws[WS_BC + c] = (conv_b[c] - bn1_m[c]) * s1 + bn1_b[c];
    }
    for (int i = gid; i < 1024; i += gsz) {
        int d = i >> 9, g = i & 511;
        ws[WS_BG + i] = d ? b_b[g] : b_f[g];
    }
    for (int i = gid; i < 768; i += gsz) {
        int d = i / 384, r = i % 384, t = r / 128, u = r % 128;
        int j = d * 128 + u;
        float s2 = bn2_g[j] / sqrtf(bn2_v[j] + 1e-5f);
        ws[WS_WFC + i] = fc_w[t * 256 + j] * s2;
    }
    for (int t = gid; t < TT; t += gsz) {
        float acc = fc_b[t];
        for (int j = 0; j < 256; ++j) {
            float s2 = bn2_g[j] / sqrtf(bn2_v[j] + 1e-5f);
            acc += fc_w[t * 256 + j] * (bn2_b[j] - bn2_m[j] * s2);
        }
        ws[WS_EB + t] = acc;
    }
    // Wt[d][k][g]: k<200 -> w_ih[g][k]; k>=200 -> w_hh[g][k-200]
    for (int i = gid; i < 2 * KA * 512; i += gsz) {
        int d = i / (KA * 512), r = i % (KA * 512), k = r / 512, g = r % 512;
        const float* wih = d ? w_ih_b : w_ih_f;
        const float* whh = d ? w_hh_b : w_hh_f;
        ws[WS_WT + i] = (k < 200) ? wih[g * 200 + k] : whh[g * HH + (k - 200)];
    }
}

// ---------------------------------------------------------------------------
// Kernel 2: fused features + BiLSTM + partial emissions.
// 256 blocks = 2 dirs x 128 tiles of NB=32 rows; 256 threads (4 waves), 1 blk/CU.
// Thread (wv=tid>>6, cg=tid&63) computes rows r0..r0+7 x units u0,u0+1 for all
// 4 gates: acc[8][8]. Weights double-buffered via global_load_lds (16B).
// Buffer schedule: chunk c in Wst[c&1]; TAIL in Wst[0] (chunk 19 occupies
// Wst[1] — R2's race was prefetching the tail into Wst[1] during chunk 19).
// ---------------------------------------------------------------------------
__global__ __launch_bounds__(256, 1)
void lstm_kernel(const int* __restrict__ x, float* __restrict__ ws)
{
    __shared__ float A[NB][336];         // [features(200) | h(128) | pad]
    __shared__ float Wst[2][16][512];    // double-buffered weight K-chunks
    __shared__ float Pp_s[3600];
    __shared__ float Wfc_s[384];
    __shared__ float biasC_s[40];

    const int tid  = threadIdx.x;
    const int d    = blockIdx.x & 1;
    const int b0   = (blockIdx.x >> 1) * NB;

    const float* Wt = ws + WS_WT + d * (KA * 512);
    float* emis = ws + WS_EMIS + d * (BB * LL * TT);

    for (int i = tid; i < 3600; i += 256) Pp_s[i] = ws[WS_P + i];
    for (int i = tid; i < 384;  i += 256) Wfc_s[i] = ws[WS_WFC + d * 384 + i];
    for (int i = tid; i < 40;   i += 256) biasC_s[i] = ws[WS_BC + i];
    for (int i = tid; i < NB * HH; i += 256) A[i >> 7][200 + (i & 127)] = 0.f;

    const int lane = tid & 63;
    const int wv   = tid >> 6;
    const int u0   = lane * 2;
    const int r0   = wv * 8;

    // gate biases, resident in regs
    const float* bg = ws + WS_BG + d * 512;
    const float bi0 = bg[u0],       bi1 = bg[u0 + 1];
    const float bf0 = bg[128 + u0], bf1 = bg[128 + u0 + 1];
    const float bg0 = bg[256 + u0], bg1 = bg[256 + u0 + 1];
    const float bo0 = bg[384 + u0], bo1 = bg[384 + u0 + 1];

    float cst[8][2];
    #pragma unroll
    for (int r = 0; r < 8; ++r) { cst[r][0] = 0.f; cst[r][1] = 0.f; }

    __syncthreads();

    for (int step = 0; step < LL; ++step) {
        const int l = d ? (LL - 1 - step) : step;

        // ---- features: conv(table lookups) + bn1 + relu + maxpool -> A[:, :200]
        for (int p = tid; p < NB * CC; p += 256) {
            int bb = p / CC, c = p % CC;
            const int* tok = x + (((b0 + bb) * LL) + l) * WW;
            int t0 = tok[0], t1 = tok[1], t2 = tok[2], t3 = tok[3], t4 = tok[4];
            float bc = biasC_s[c];
            float a0 = bc + Pp_s[(30 + t0) * 40 + c] + Pp_s[(60 + t1) * 40 + c];
            float a1 = bc + Pp_s[t0 * 40 + c] + Pp_s[(30 + t1) * 40 + c] + Pp_s[(60 + t2) * 40 + c];
            float a2 = bc + Pp_s[t1 * 40 + c] + Pp_s[(30 + t2) * 40 + c] + Pp_s[(60 + t3) * 40 + c];
            float a3 = bc + Pp_s[t2 * 40 + c] + Pp_s[(30 + t3) * 40 + c] + Pp_s[(60 + t4) * 40 + c];
            float a4 = bc + Pp_s[t3 * 40 + c] + Pp_s[(30 + t4) * 40 + c];
            a0 = fmaxf(a0, 0.f); a1 = fmaxf(a1, 0.f); a2 = fmaxf(a2, 0.f);
            a3 = fmaxf(a3, 0.f); a4 = fmaxf(a4, 0.f);
            float* Af = &A[bb][c * 5];
            Af[0] = fmaxf(a0, a1);
            Af[1] = fmaxf(fmaxf(a0, a1), a2);
            Af[2] = fmaxf(fmaxf(a1, a2), a3);
            Af[3] = fmaxf(fmaxf(a2, a3), a4);
            Af[4] = fmaxf(a3, a4);
        }

        // async-stage chunk 0 while features settle at the barrier
        {
            const float* gb = Wt;                       // k0 = 0
            #pragma unroll
            for (int i = 0; i < 8; ++i) {
                int blk = wv * 8 + i;
                async_copy16(gb + blk * 256 + lane * 4, &Wst[0][0][0] + blk * 256);
            }
        }
        __syncthreads();   // features visible + chunk0 DMA drained

        float acc[8][8];
        #pragma unroll
        for (int r = 0; r < 8; ++r)
            #pragma unroll
            for (int j = 0; j < 8; ++j) acc[r][j] = 0.f;

        // ---- 20 full chunks of 16 k-rows ----
        for (int c = 0; c < 20; ++c) {
            // prefetch next chunk into the buffer NOT in use this iteration
            if (c < 19) {
                const float* gb = Wt + (c + 1) * 16 * 512;
                #pragma unroll
                for (int i = 0; i < 8; ++i) {
                    int blk = wv * 8 + i;
                    async_copy16(gb + blk * 256 + lane * 4, &Wst[(c + 1) & 1][0][0] + blk * 256);
                }
            } else {
                // tail chunk (k=320..327) -> Wst[0]; chunk 19 computes from Wst[1]
                const float* gb = Wt + 320 * 512;
                #pragma unroll
                for (int i = 0; i < 4; ++i) {
                    int blk = wv * 4 + i;
                    async_copy16(gb + blk * 256 + lane * 4, &Wst[0][0][0] + blk * 256);
                }
            }
            const float* Wb = &Wst[c & 1][0][0];
            const int kc = c * 16;
            #pragma unroll
            for (int kg = 0; kg < 4; ++kg) {
                float a4[8][4];
                #pragma unroll
                for (int r = 0; r < 8; ++r) {
                    float4 t = *(const float4*)&A[r0 + r][kc + kg * 4];
                    a4[r][0] = t.x; a4[r][1] = t.y; a4[r][2] = t.z; a4[r][3] = t.w;
                }
                #pragma unroll
                for (int k2 = 0; k2 < 4; ++k2) {
                    const float* wrow = Wb + (kg * 4 + k2) * 512 + u0;
                    float2 w0 = *(const float2*)(wrow);
                    float2 w1 = *(const float2*)(wrow + 128);
                    float2 w2 = *(const float2*)(wrow + 256);
                    float2 w3 = *(const float2*)(wrow + 384);
                    #pragma unroll
                    for (int r = 0; r < 8; ++r) {
                        float a = a4[r][k2];
                        acc[r][0] = fmaf(a, w0.x, acc[r][0]);
                        acc[r][1] = fmaf(a, w0.y, acc[r][1]);
                        acc[r][2] = fmaf(a, w1.x, acc[r][2]);
                        acc[r][3] = fmaf(a, w1.y, acc[r][3]);
                        acc[r][4] = fmaf(a, w2.x, acc[r][4]);
                        acc[r][5] = fmaf(a, w2.y, acc[r][5]);
                        acc[r][6] = fmaf(a, w3.x, acc[r][6]);
                        acc[r][7] = fmaf(a, w3.y, acc[r][7]);
                    }
                }
            }
            __syncthreads();   // drains next-chunk DMA; protects buffer reuse
        }
        // ---- tail chunk: k = 320..327 in Wst[0] ----
        {
            const float* Wb = &Wst[0][0][0];
            #pragma unroll
            for (int kg = 0; kg < 2; ++kg) {
                float a4[8][4];
                #pragma unroll
                for (int r = 0; r < 8; ++r) {
                    float4 t = *(const float4*)&A[r0 + r][320 + kg * 4];
                    a4[r][0] = t.x; a4[r][1] = t.y; a4[r][2] = t.z; a4[r][3] = t.w;
                }
                #pragma unroll
                for (int k2 = 0; k2 < 4; ++k2) {
                    const float* wrow = Wb + (kg * 4 + k2) * 512 + u0;
                    float2 w0 = *(const float2*)(wrow);
                    float2 w1 = *(const float2*)(wrow + 128);
                    float2 w2 = *(const float2*)(wrow + 256);
                    float2 w3 = *(const float2*)(wrow + 384);
                    #pragma unroll
                    for (int r = 0; r < 8; ++r) {
                        float a = a4[r][k2];
                        acc[r][0] = fmaf(a, w0.x, acc[r][0]);
                        acc[r][1] = fmaf(a, w0.y, acc[r][1]);
                        acc[r][2] = fmaf(a, w1.x, acc[r][2]);
                        acc[r][3] = fmaf(a, w1.y, acc[r][3]);
                        acc[r][4] = fmaf(a, w2.x, acc[r][4]);
                        acc[r][5] = fmaf(a, w2.y, acc[r][5]);
                        acc[r][6] = fmaf(a, w3.x, acc[r][6]);
                        acc[r][7] = fmaf(a, w3.y, acc[r][7]);
                    }
                }
            }
        }

        // ---- gates (thread-local) -> h into A[:, 200:328] ----
        #pragma unroll
        for (int r = 0; r < 8; ++r) {
            float zi0 = acc[r][0] + bi0, zi1 = acc[r][1] + bi1;
            float zf0 = acc[r][2] + bf0, zf1 = acc[r][3] + bf1;
            float zg0 = acc[r][4] + bg0, zg1 = acc[r][5] + bg1;
            float zo0 = acc[r][6] + bo0, zo1 = acc[r][7] + bo1;
            float c0 = sigm(zf0) * cst[r][0] + sigm(zi0) * tanh_fast(zg0);
            float c1 = sigm(zf1) * cst[r][1] + sigm(zi1) * tanh_fast(zg1);
            cst[r][0] = c0; cst[r][1] = c1;
            float2 h2;
            h2.x = sigm(zo0) * tanh_fast(c0);
            h2.y = sigm(zo1) * tanh_fast(c1);
            *(float2*)&A[r0 + r][200 + u0] = h2;
        }
        __syncthreads();   // h visible to emission readers

        // ---- partial emissions: 32 rows x 3 tags, split in 2 segments ----
        if (tid < 192) {
            int bb = tid / 6, r6 = tid % 6, t = r6 >> 1, seg = r6 & 1;
            const float* hv = &A[bb][200 + seg * 64];
            const float* wfc = &Wfc_s[t * 128 + seg * 64];
            float s = 0.f;
            #pragma unroll
            for (int i = 0; i < 16; ++i) {
                float4 ha = *(const float4*)(hv + i * 4);
                float4 wa = *(const float4*)(wfc + i * 4);
                s += ha.x * wa.x + ha.y * wa.y + ha.z * wa.z + ha.w * wa.w;
            }
            s += __shfl_xor(s, 1);
            if (seg == 0)
                emis[(((b0 + bb) * LL) + l) * TT + t] = s;
        }
        // next features phase writes A[:, :200] only; h region stays intact
        // until next gates phase — no barrier needed here.
    }
}

// ---------------------------------------------------------------------------
// Kernel 3: Viterbi decode. One thread per batch row.
// ---------------------------------------------------------------------------
__global__ void viterbi_kernel(const int* __restrict__ x, const float* __restrict__ ws,
                               const float* __restrict__ trans,
                               const float* __restrict__ start_t,
                               const float* __restrict__ end_t,
                               float* __restrict__ out)
{
    int b = blockIdx.x * blockDim.x + threadIdx.x;
    if (b >= BB) return;
    const float* eF = ws + WS_EMIS;
    const float* eB = ws + WS_EMIS + BB * LL * TT;
    const float eb0 = ws[WS_EB + 0], eb1 = ws[WS_EB + 1], eb2 = ws[WS_EB + 2];
    float tr[9];
    #pragma unroll
    for (int i = 0; i < 9; ++i) tr[i] = trans[i];

    int base = b * LL * TT;
    float s0 = start_t[0] + eF[base + 0] + eB[base + 0] + eb0;
    float s1 = start_t[1] + eF[base + 1] + eB[base + 1] + eb1;
    float s2 = start_t[2] + eF[base + 2] + eB[base + 2] + eb2;

    unsigned hist[LL - 1];
    unsigned maskbits = 0;

    #pragma unroll
    for (int l = 1; l < LL; ++l) {
        bool m = x[(b * LL + l) * WW + 2] > 0;
        if (m) maskbits |= (1u << l);
        int idx = base + l * TT;
        float e0 = eF[idx + 0] + eB[idx + 0] + eb0;
        float e1 = eF[idx + 1] + eB[idx + 1] + eb1;
        float e2 = eF[idx + 2] + eB[idx + 2] + eb2;

        float ns[3]; int pt[3];
        #pragma unroll
        for (int nt = 0; nt < 3; ++nt) {
            float c0 = s0 + tr[0 * 3 + nt];
            float c1 = s1 + tr[1 * 3 + nt];
            float c2 = s2 + tr[2 * 3 + nt];
            int p = 0; float bc = c0;
            if (c1 > bc) { bc = c1; p = 1; }   // strict '>': first-index argmax
            if (c2 > bc) { bc = c2; p = 2; }
            ns[nt] = bc; pt[nt] = p;
        }
        ns[0] += e0; ns[1] += e1; ns[2] += e2;
        hist[l - 1] = (unsigned)pt[0] | ((unsigned)pt[1] << 2) | ((unsigned)pt[2] << 4);
        if (m) { s0 = ns[0]; s1 = ns[1]; s2 = ns[2]; }
    }
    s0 += end_t[0]; s1 += end_t[1]; s2 += end_t[2];
    float best = s0; int last = 0;
    if (s1 > best) { best = s1; last = 1; }
    if (s2 > best) { best = s2; last = 2; }

    out[b] = best;
    float* tags = out + BB + b * LL;
    int tag = last;
    tags[LL - 1] = (float)last;
    #pragma unroll
    for (int l = LL - 1; l >= 1; --l) {
        int prev = (int)((hist[l - 1] >> (2 * tag)) & 3u);
        if (maskbits & (1u << l)) tag = prev;
        tags[l - 1] = (float)tag;
    }
}

// ---------------------------------------------------------------------------
extern "C" void kernel_launch(void* const* d_in, const int* in_sizes, int n_in,
                              void* d_out, int out_size, void* d_ws, size_t ws_size,
                              hipStream_t stream)
{
    const int*   x      = (const int*)  d_in[0];
    const float* emb    = (const float*)d_in[1];
    const float* conv_w = (const float*)d_in[2];
    const float* conv_b = (const float*)d_in[3];
    const float* bn1_g  = (const float*)d_in[4];
    const float* bn1_b  = (const float*)d_in[5];
    const float* bn1_m  = (const float*)d_in[6];
    const float* bn1_v  = (const float*)d_in[7];
    const float* w_ih_f = (const float*)d_in[8];
    const float* w_hh_f = (const float*)d_in[9];
    const float* b_f    = (const float*)d_in[10];
    const float* w_ih_b = (const float*)d_in[11];
    const float* w_hh_b = (const float*)d_in[12];
    const float* b_b    = (const float*)d_in[13];
    const float* bn2_g  = (const float*)d_in[14];
    const float* bn2_b  = (const float*)d_in[15];
    const float* bn2_m  = (const float*)d_in[16];
    const float* bn2_v  = (const float*)d_in[17];
    const float* fc_w   = (const float*)d_in[18];
    const float* fc_b   = (const float*)d_in[19];
    const float* trans  = (const float*)d_in[20];
    const float* start_t= (const float*)d_in[21];
    const float* end_t  = (const float*)d_in[22];

    float* ws  = (float*)d_ws;
    float* out = (float*)d_out;

    prep_kernel<<<256, 256, 0, stream>>>(emb, conv_w, conv_b,
                                         bn1_g, bn1_b, bn1_m, bn1_v,
                                         w_ih_f, w_hh_f, b_f,
                                         w_ih_b, w_hh_b, b_b,
                                         bn2_g, bn2_b, bn2_m, bn2_v,
                                         fc_w, fc_b, ws);
    lstm_kernel<<<256, 256, 0, stream>>>(x, ws);
    viterbi_kernel<<<16, 256, 0, stream>>>(x, ws, trans, start_t, end_t, out);
}